// Round 5
// baseline (684.513 us; speedup 1.0000x reference)
//
#include <hip/hip_runtime.h>

#define CC    64
#define HH    3
#define ECC   32
#define HCdim 192
#define NEG_SLOPE 0.2f

typedef float v2f __attribute__((ext_vector_type(2)));

// ---- float <-> monotone uint key (for atomicMax on floats) ----
__device__ __forceinline__ unsigned fkey(float f) {
    int i = __float_as_int(f);
    return (i < 0) ? ~((unsigned)i) : (((unsigned)i) | 0x80000000u);
}
__device__ __forceinline__ float funkey(unsigned k) {
    int i = (k & 0x80000000u) ? (int)(k ^ 0x80000000u) : ~((int)k);
    return __int_as_float(i);
}

// K0: u[h*32+k] = sum_c We[k*192 + h*64 + c] * wt[h*192 + 64 + c]
__global__ void tm_k0(const float* __restrict__ We, const float* __restrict__ wt,
                      float* __restrict__ u) {
    int t = threadIdx.x;
    if (t >= HH * ECC) return;
    int h = t >> 5, k = t & 31;
    float s = 0.f;
    #pragma unroll
    for (int c = 0; c < CC; ++c)
        s = fmaf(We[k * HCdim + h * CC + c], wt[h * HCdim + CC + c], s);
    u[t] = s;
}

// K1: xp = x @ Wn (N x 64 @ 64 x 192) with 8-row register blocking.
// Fused: deg histogram over dst, and per-node attention scalars sA.
#define K1_ROWS 64
__global__ __launch_bounds__(192) void tm_k1(const float* __restrict__ x,
        const float* __restrict__ Wn, const float* __restrict__ wt,
        const int* __restrict__ ei, int* __restrict__ deg,
        float* __restrict__ xp, float* __restrict__ sA, int N, int E) {
    __shared__ float wl[CC * HCdim];     // 48 KiB  [k][t]
    __shared__ float xl[K1_ROWS * CC];   // 16 KiB  [r][k]
    const int t = threadIdx.x;
    // fused deg histogram (overlaps LDS staging; fire-and-forget atomics)
    for (int i = blockIdx.x * 192 + t; i < E; i += gridDim.x * 192)
        atomicAdd(&deg[ei[E + i]], 1);
    const int h = t >> 6, c = t & 63;
    {
        float4* wl4 = (float4*)wl;
        const float4* Wn4 = (const float4*)Wn;
        for (int i = t; i < CC * HCdim / 4; i += 192) wl4[i] = Wn4[i];
    }
    const int base = blockIdx.x * K1_ROWS;
    const int rows = min(K1_ROWS, N - base);
    {
        float4* xl4 = (float4*)xl;
        const float4* x4 = (const float4*)(x + (size_t)base * CC);
        for (int i = t; i < rows * CC / 4; i += 192) xl4[i] = x4[i];
    }
    const float w0c = wt[h * HCdim + c];
    const float w2c = wt[h * HCdim + 2 * CC + c];
    __syncthreads();
    for (int rt = 0; rt < K1_ROWS / 8; ++rt) {
        float acc[8] = {0.f, 0.f, 0.f, 0.f, 0.f, 0.f, 0.f, 0.f};
        for (int k = 0; k < CC; k += 4) {
            const float w0  = wl[(k + 0) * HCdim + t];
            const float w1  = wl[(k + 1) * HCdim + t];
            const float w2_ = wl[(k + 2) * HCdim + t];
            const float w3  = wl[(k + 3) * HCdim + t];
            #pragma unroll
            for (int r = 0; r < 8; ++r) {
                const float4 xv = *(const float4*)&xl[(rt * 8 + r) * CC + k];
                acc[r] = fmaf(xv.x, w0,
                         fmaf(xv.y, w1,
                         fmaf(xv.z, w2_,
                         fmaf(xv.w, w3, acc[r]))));
            }
        }
        #pragma unroll
        for (int r = 0; r < 8; ++r) {
            const int rr = rt * 8 + r;
            if (rr < rows) {
                const int n = base + rr;
                xp[(size_t)n * HCdim + t] = acc[r];
                float a0 = acc[r] * w0c, a2 = acc[r] * w2c;
                #pragma unroll
                for (int o = 32; o; o >>= 1) {
                    a0 += __shfl_xor(a0, o);
                    a2 += __shfl_xor(a2, o);
                }
                if (c == 0) {
                    sA[n * 8 + h]     = a0;
                    sA[n * 8 + 4 + h] = a2;
                }
            }
        }
    }
}

// scanA: per-block (256) sums of deg
__global__ __launch_bounds__(256) void tm_scanA(const int* __restrict__ deg,
        int* __restrict__ bsum, int N) {
    __shared__ int sd[256];
    int t = threadIdx.x, n = blockIdx.x * 256 + t;
    sd[t] = (n < N) ? deg[n] : 0;
    __syncthreads();
    for (int o = 128; o; o >>= 1) {
        if (t < o) sd[t] += sd[t + o];
        __syncthreads();
    }
    if (!t) bsum[blockIdx.x] = sd[0];
}

// scanB: exclusive scan of block sums (nb <= 256), single block
__global__ __launch_bounds__(256) void tm_scanB(const int* __restrict__ bsum,
        int* __restrict__ boff, int nb) {
    __shared__ int sd[256];
    int t = threadIdx.x;
    int v = (t < nb) ? bsum[t] : 0;
    sd[t] = v;
    __syncthreads();
    for (int o = 1; o < 256; o <<= 1) {
        int x = (t >= o) ? sd[t - o] : 0;
        __syncthreads();
        sd[t] += x;
        __syncthreads();
    }
    if (t < nb) boff[t] = sd[t] - v;   // exclusive
}

// scanC: per-element exclusive offsets; off[N]=E; cursor=off copy
__global__ __launch_bounds__(256) void tm_scanC(const int* __restrict__ deg,
        const int* __restrict__ boff, int* __restrict__ off,
        int* __restrict__ cursor, int N) {
    __shared__ int sd[256];
    int t = threadIdx.x, n = blockIdx.x * 256 + t;
    int v = (n < N) ? deg[n] : 0;
    sd[t] = v;
    __syncthreads();
    for (int o = 1; o < 256; o <<= 1) {
        int x = (t >= o) ? sd[t - o] : 0;
        __syncthreads();
        sd[t] += x;
        __syncthreads();
    }
    if (n < N) {
        int ex = boff[blockIdx.x] + sd[t] - v;
        off[n] = ex;
        cursor[n] = ex;
        if (n == N - 1) off[N] = ex + v;
    }
}

// K_scatter2: per edge - pos = cursor[dst]++;
//   perm[pos] = {src byte-offset into xp, e byte-offset into ea};
//   alphaS[h*E+pos] = leaky(s0[dst,h] + ea[e].u[h] + s2[src,h]);
//   atomicMax(segmax[dst*3+h]).
__global__ __launch_bounds__(256) void tm_scatter2(const int* __restrict__ ei,
        const float* __restrict__ ea, const float* __restrict__ u,
        const float* __restrict__ sA, int* __restrict__ cursor,
        int2* __restrict__ perm, float* __restrict__ alphaS,
        unsigned* __restrict__ segmax, int E) {
    __shared__ float ul[HH * ECC];
    const int t = threadIdx.x;
    if (t < HH * ECC) ul[t] = u[t];
    __syncthreads();
    const int e = blockIdx.x * 256 + t;
    if (e >= E) return;
    const int src = ei[e];
    const int dst = ei[E + e];
    float av[ECC];
    const float4* p4 = (const float4*)(ea + (size_t)e * ECC);
    #pragma unroll
    for (int q = 0; q < 8; ++q) {
        float4 v = p4[q];
        av[4*q] = v.x; av[4*q+1] = v.y; av[4*q+2] = v.z; av[4*q+3] = v.w;
    }
    float d0 = 0.f, d1 = 0.f, d2 = 0.f;
    #pragma unroll
    for (int k = 0; k < ECC; ++k) {
        d0 = fmaf(av[k], ul[k], d0);
        d1 = fmaf(av[k], ul[ECC + k], d1);
        d2 = fmaf(av[k], ul[2 * ECC + k], d2);
    }
    const float4 s0 = *(const float4*)(sA + (size_t)dst * 8);
    const float4 s2 = *(const float4*)(sA + (size_t)src * 8 + 4);
    float a0 = s0.x + d0 + s2.x;
    float a1 = s0.y + d1 + s2.y;
    float a2 = s0.z + d2 + s2.z;
    a0 = (a0 >= 0.f) ? a0 : NEG_SLOPE * a0;
    a1 = (a1 >= 0.f) ? a1 : NEG_SLOPE * a1;
    a2 = (a2 >= 0.f) ? a2 : NEG_SLOPE * a2;
    const int pos = atomicAdd(&cursor[dst], 1);
    perm[pos] = make_int2(src * (HCdim * 4), e * (ECC * 4));
    alphaS[pos]         = a0;
    alphaS[E + pos]     = a1;
    alphaS[2 * E + pos] = a2;
    atomicMax(&segmax[dst * 3 + 0], fkey(a0));
    atomicMax(&segmax[dst * 3 + 1], fkey(a1));
    atomicMax(&segmax[dst * 3 + 2], fkey(a2));
}

// K_agg: one block (3 waves = 3 heads) per dst node. Branch-free inner loop,
// packed-f32 dot (v_pk_fma_f32), byte-offset addressing, 2x unroll.
__global__ __launch_bounds__(192) void tm_agg(const int2* __restrict__ perm,
        const int* __restrict__ off, const float* __restrict__ ea,
        const float* __restrict__ We, const float* __restrict__ alphaS,
        const unsigned* __restrict__ segmax, const float* __restrict__ xp,
        float* __restrict__ aggrN, int N, int E) {
    const int n = blockIdx.x;
    const int t = threadIdx.x;
    const int h = t >> 6, lane = t & 63;
    const char* __restrict__ ea_b = (const char*)ea;
    const char* __restrict__ xp_b = (const char*)xp;
    v2f wcol2[16];
    #pragma unroll
    for (int k2 = 0; k2 < 16; ++k2) {
        wcol2[k2].x = We[(2 * k2)     * HCdim + h * CC + lane];
        wcol2[k2].y = We[(2 * k2 + 1) * HCdim + h * CC + lane];
    }
    const float m = funkey(segmax[n * 3 + h]);
    const float* __restrict__ alphaH = alphaS + (size_t)h * E;
    const int xoff = h * CC * 4 + lane * 4;  // byte offset within an xp row
    const int start = off[n], end = off[n + 1];
    float s = 0.f, acc = 0.f;
    int pos = start;
    for (; pos + 2 <= end; pos += 2) {
        const int2 pe0 = perm[pos];
        const int2 pe1 = perm[pos + 1];
        const int so0 = __builtin_amdgcn_readfirstlane(pe0.x);
        const int eo0 = __builtin_amdgcn_readfirstlane(pe0.y);
        const int so1 = __builtin_amdgcn_readfirstlane(pe1.x);
        const int eo1 = __builtin_amdgcn_readfirstlane(pe1.y);
        const float a0 = alphaH[pos], a1 = alphaH[pos + 1];
        const float4* q0 = (const float4*)(ea_b + eo0);
        const float4* q1 = (const float4*)(ea_b + eo1);
        const float xj0 = *(const float*)(xp_b + so0 + xoff);
        const float xj1 = *(const float*)(xp_b + so1 + xoff);
        v2f d0 = {0.f, 0.f}, d1 = {0.f, 0.f};
        #pragma unroll
        for (int q = 0; q < 8; ++q) {
            const float4 v0 = q0[q];
            const float4 v1 = q1[q];
            v2f lo0 = {v0.x, v0.y}, hi0 = {v0.z, v0.w};
            v2f lo1 = {v1.x, v1.y}, hi1 = {v1.z, v1.w};
            d0 = lo0 * wcol2[2 * q]     + d0;
            d0 = hi0 * wcol2[2 * q + 1] + d0;
            d1 = lo1 * wcol2[2 * q]     + d1;
            d1 = hi1 * wcol2[2 * q + 1] + d1;
        }
        const float p0 = __expf(a0 - m);
        const float p1 = __expf(a1 - m);
        s += p0 + p1;
        acc = fmaf(p0 * (d0.x + d0.y), xj0, acc);
        acc = fmaf(p1 * (d1.x + d1.y), xj1, acc);
    }
    if (pos < end) {
        const int2 pe = perm[pos];
        const int so = __builtin_amdgcn_readfirstlane(pe.x);
        const int eo = __builtin_amdgcn_readfirstlane(pe.y);
        const float a = alphaH[pos];
        const float4* q4 = (const float4*)(ea_b + eo);
        const float xj = *(const float*)(xp_b + so + xoff);
        v2f d = {0.f, 0.f};
        #pragma unroll
        for (int q = 0; q < 8; ++q) {
            const float4 v = q4[q];
            v2f lo = {v.x, v.y}, hi = {v.z, v.w};
            d = lo * wcol2[2 * q]     + d;
            d = hi * wcol2[2 * q + 1] + d;
        }
        const float p = __expf(a - m);
        s += p;
        acc = fmaf(p * (d.x + d.y), xj, acc);
    }
    aggrN[(size_t)n * HCdim + h * CC + lane] = acc / (s + 1e-16f);
}

// K5: out[n,:] = aggrN[n,:] @ Ws + bias   (aggrN already normalized)
__global__ __launch_bounds__(256) void tm_k5(const float* __restrict__ aggrN,
        const float* __restrict__ Ws, const float* __restrict__ bias,
        float* __restrict__ out, int N) {
    __shared__ float wsl[HCdim * CC];   // 48 KiB
    __shared__ float al[4][HCdim];
    const int t = threadIdx.x;
    const int wv = t >> 6, lane = t & 63;
    for (int i = t; i < HCdim * CC; i += 256) wsl[i] = Ws[i];
    const float b = bias[lane];
    for (int base = blockIdx.x * 4; base < N; base += gridDim.x * 4) {
        const int n = base + wv;
        __syncthreads();
        if (n < N) {
            for (int i = lane; i < HCdim; i += 64)
                al[wv][i] = aggrN[(size_t)n * HCdim + i];
        }
        __syncthreads();
        if (n < N) {
            float acc = b;
            #pragma unroll
            for (int k = 0; k < HCdim; ++k)
                acc = fmaf(al[wv][k], wsl[k * CC + lane], acc);
            out[(size_t)n * CC + lane] = acc;
        }
    }
}

extern "C" void kernel_launch(void* const* d_in, const int* in_sizes, int n_in,
                              void* d_out, int out_size, void* d_ws, size_t ws_size,
                              hipStream_t stream) {
    const float* x    = (const float*)d_in[0];
    const int*   ei   = (const int*)d_in[1];
    const float* ea   = (const float*)d_in[2];
    const float* Wn   = (const float*)d_in[3];
    const float* We   = (const float*)d_in[4];
    const float* wt   = (const float*)d_in[5];
    const float* Ws   = (const float*)d_in[6];
    const float* bias = (const float*)d_in[7];
    float* out = (float*)d_out;
    const int N = in_sizes[0] / CC;
    const int E = in_sizes[1] / 2;
    const int nb = (N + 255) / 256;          // scan blocks (<= 256)
    const int k1blocks = (N + K1_ROWS - 1) / K1_ROWS;

    // workspace layout (floats; 16B alignment kept for float4/int2 buffers)
    float* ws = (float*)d_ws;
    size_t o = 0;
    float* xp = ws + o;                  o += (size_t)N * HCdim;   // 38.4 MB
    float* sA = ws + o;                  o += (size_t)N * 8;       // 1.6 MB
    float* u  = ws + o;                  o += 128;
    float* alphaS = ws + o;              o += (size_t)E * HH;      // 9.6 MB
    o += (4 - (o & 3)) & 3;              // 16B align
    int2*  perm = (int2*)(ws + o);       o += (size_t)E * 2;       // 6.4 MB
    int* deg    = (int*)(ws + o);        o += N;
    unsigned* segmax = (unsigned*)(ws + o); o += (size_t)N * HH;
    int* off    = (int*)(ws + o);        o += N + 1;
    int* cursor = (int*)(ws + o);        o += N;
    int* bsum   = (int*)(ws + o);        o += 256;
    int* boff   = (int*)(ws + o);        o += 256;
    o += (4 - (o & 3)) & 3;              // realign
    float* aggrN = ws + o;               o += (size_t)N * HCdim;   // 38.4 MB
    (void)ws_size; (void)n_in; (void)out_size;

    // zero deg + segmax (adjacent)
    (void)hipMemsetAsync(deg, 0, (size_t)N * (1 + HH) * sizeof(int), stream);

    tm_k0<<<1, 96, 0, stream>>>(We, wt, u);
    tm_k1<<<k1blocks, 192, 0, stream>>>(x, Wn, wt, ei, deg, xp, sA, N, E);
    tm_scanA<<<nb, 256, 0, stream>>>(deg, bsum, N);
    tm_scanB<<<1, 256, 0, stream>>>(bsum, boff, nb);
    tm_scanC<<<nb, 256, 0, stream>>>(deg, boff, off, cursor, N);
    tm_scatter2<<<(E + 255) / 256, 256, 0, stream>>>(ei, ea, u, sA, cursor,
                                                     perm, alphaS, segmax, E);
    tm_agg<<<N, 192, 0, stream>>>(perm, off, ea, We, alphaS, segmax, xp,
                                  aggrN, N, E);
    tm_k5<<<2048, 256, 0, stream>>>(aggrN, Ws, bias, out, N);
}

// Round 6
// 521.062 us; speedup vs baseline: 1.3137x; 1.3137x over previous
//
#include <hip/hip_runtime.h>

#define CC    64
#define HH    3
#define ECC   32
#define HCdim 192
#define NEG_SLOPE 0.2f

typedef float v2f __attribute__((ext_vector_type(2)));

// ---- float <-> monotone uint key (for atomicMax on floats) ----
__device__ __forceinline__ unsigned fkey(float f) {
    int i = __float_as_int(f);
    return (i < 0) ? ~((unsigned)i) : (((unsigned)i) | 0x80000000u);
}
__device__ __forceinline__ float funkey(unsigned k) {
    int i = (k & 0x80000000u) ? (int)(k ^ 0x80000000u) : ~((int)k);
    return __int_as_float(i);
}

// K0: u[h*32+k] = sum_c We[k*192 + h*64 + c] * wt[h*192 + 64 + c]
__global__ void tm_k0(const float* __restrict__ We, const float* __restrict__ wt,
                      float* __restrict__ u) {
    int t = threadIdx.x;
    if (t >= HH * ECC) return;
    int h = t >> 5, k = t & 31;
    float s = 0.f;
    #pragma unroll
    for (int c = 0; c < CC; ++c)
        s = fmaf(We[k * HCdim + h * CC + c], wt[h * HCdim + CC + c], s);
    u[t] = s;
}

// K1 (R4 version): xp = x @ Wn (N x 64 @ 64 x 192), fused per-node scalars:
//     sA[n*8+h]   = xp[n,h,:] . w0[h]
//     sA[n*8+4+h] = xp[n,h,:] . w2[h]
#define K1_ROWS 64
__global__ __launch_bounds__(192) void tm_k1(const float* __restrict__ x,
        const float* __restrict__ Wn, const float* __restrict__ wt,
        float* __restrict__ xp, float* __restrict__ sA, int N) {
    __shared__ float wl[CC * HCdim];     // 48 KiB
    __shared__ float xl[K1_ROWS * CC];   // 16 KiB
    const int t = threadIdx.x;
    const int h = t >> 6, c = t & 63;
    for (int i = t; i < CC * HCdim; i += 192) wl[i] = Wn[i];
    const float w0c = wt[h * HCdim + c];
    const float w2c = wt[h * HCdim + 2 * CC + c];
    const int base = blockIdx.x * K1_ROWS;
    const int rows = min(K1_ROWS, N - base);
    for (int i = t; i < rows * CC; i += 192) xl[i] = x[(size_t)base * CC + i];
    __syncthreads();
    for (int r = 0; r < rows; ++r) {
        float v = 0.f;
        #pragma unroll
        for (int k = 0; k < CC; ++k)
            v = fmaf(xl[r * CC + k], wl[k * HCdim + t], v);
        const int n = base + r;
        xp[(size_t)n * HCdim + t] = v;
        float a0 = v * w0c, a2 = v * w2c;
        #pragma unroll
        for (int off = 32; off; off >>= 1) {
            a0 += __shfl_xor(a0, off);
            a2 += __shfl_xor(a2, off);
        }
        if (c == 0) {
            sA[n * 8 + h]     = a0;
            sA[n * 8 + 4 + h] = a2;
        }
    }
}

// K_deg: degree histogram over dst
__global__ __launch_bounds__(256) void tm_deg(const int* __restrict__ ei,
        int* __restrict__ deg, int E) {
    int e = blockIdx.x * 256 + threadIdx.x;
    if (e < E) atomicAdd(&deg[ei[E + e]], 1);
}

// scanA: per-block (256) sums of deg
__global__ __launch_bounds__(256) void tm_scanA(const int* __restrict__ deg,
        int* __restrict__ bsum, int N) {
    __shared__ int sd[256];
    int t = threadIdx.x, n = blockIdx.x * 256 + t;
    sd[t] = (n < N) ? deg[n] : 0;
    __syncthreads();
    for (int o = 128; o; o >>= 1) {
        if (t < o) sd[t] += sd[t + o];
        __syncthreads();
    }
    if (!t) bsum[blockIdx.x] = sd[0];
}

// scanB: exclusive scan of block sums (nb <= 256), single block
__global__ __launch_bounds__(256) void tm_scanB(const int* __restrict__ bsum,
        int* __restrict__ boff, int nb) {
    __shared__ int sd[256];
    int t = threadIdx.x;
    int v = (t < nb) ? bsum[t] : 0;
    sd[t] = v;
    __syncthreads();
    for (int o = 1; o < 256; o <<= 1) {
        int x = (t >= o) ? sd[t - o] : 0;
        __syncthreads();
        sd[t] += x;
        __syncthreads();
    }
    if (t < nb) boff[t] = sd[t] - v;   // exclusive
}

// scanC: per-element exclusive offsets; off[N]=E; cursor=off copy
__global__ __launch_bounds__(256) void tm_scanC(const int* __restrict__ deg,
        const int* __restrict__ boff, int* __restrict__ off,
        int* __restrict__ cursor, int N) {
    __shared__ int sd[256];
    int t = threadIdx.x, n = blockIdx.x * 256 + t;
    int v = (n < N) ? deg[n] : 0;
    sd[t] = v;
    __syncthreads();
    for (int o = 1; o < 256; o <<= 1) {
        int x = (t >= o) ? sd[t - o] : 0;
        __syncthreads();
        sd[t] += x;
        __syncthreads();
    }
    if (n < N) {
        int ex = boff[blockIdx.x] + sd[t] - v;
        off[n] = ex;
        cursor[n] = ex;
        if (n == N - 1) off[N] = ex + v;
    }
}

// K_scatter2: per edge - pos = cursor[dst]++;
//   perm[pos] = {src byte-offset into xp, e byte-offset into ea};
//   alphaS[h*E+pos] = leaky(s0[dst,h] + ea[e].u[h] + s2[src,h]);
//   atomicMax(segmax[dst*3+h]).
__global__ __launch_bounds__(256) void tm_scatter2(const int* __restrict__ ei,
        const float* __restrict__ ea, const float* __restrict__ u,
        const float* __restrict__ sA, int* __restrict__ cursor,
        int2* __restrict__ perm, float* __restrict__ alphaS,
        unsigned* __restrict__ segmax, int E) {
    __shared__ float ul[HH * ECC];
    const int t = threadIdx.x;
    if (t < HH * ECC) ul[t] = u[t];
    __syncthreads();
    const int e = blockIdx.x * 256 + t;
    if (e >= E) return;
    const int src = ei[e];
    const int dst = ei[E + e];
    float av[ECC];
    const float4* p4 = (const float4*)(ea + (size_t)e * ECC);
    #pragma unroll
    for (int q = 0; q < 8; ++q) {
        float4 v = p4[q];
        av[4*q] = v.x; av[4*q+1] = v.y; av[4*q+2] = v.z; av[4*q+3] = v.w;
    }
    float d0 = 0.f, d1 = 0.f, d2 = 0.f;
    #pragma unroll
    for (int k = 0; k < ECC; ++k) {
        d0 = fmaf(av[k], ul[k], d0);
        d1 = fmaf(av[k], ul[ECC + k], d1);
        d2 = fmaf(av[k], ul[2 * ECC + k], d2);
    }
    const float4 s0 = *(const float4*)(sA + (size_t)dst * 8);
    const float4 s2 = *(const float4*)(sA + (size_t)src * 8 + 4);
    float a0 = s0.x + d0 + s2.x;
    float a1 = s0.y + d1 + s2.y;
    float a2 = s0.z + d2 + s2.z;
    a0 = (a0 >= 0.f) ? a0 : NEG_SLOPE * a0;
    a1 = (a1 >= 0.f) ? a1 : NEG_SLOPE * a1;
    a2 = (a2 >= 0.f) ? a2 : NEG_SLOPE * a2;
    const int pos = atomicAdd(&cursor[dst], 1);
    perm[pos] = make_int2(src * (HCdim * 4), e * (ECC * 4));
    alphaS[pos]         = a0;
    alphaS[E + pos]     = a1;
    alphaS[2 * E + pos] = a2;
    atomicMax(&segmax[dst * 3 + 0], fkey(a0));
    atomicMax(&segmax[dst * 3 + 1], fkey(a1));
    atomicMax(&segmax[dst * 3 + 2], fkey(a2));
}

// K_agg: one block (3 waves = 3 heads) per dst node. Branch-free inner loop,
// packed-f32 dot (v_pk_fma_f32), byte-offset addressing, 2x unroll.
__global__ __launch_bounds__(192) void tm_agg(const int2* __restrict__ perm,
        const int* __restrict__ off, const float* __restrict__ ea,
        const float* __restrict__ We, const float* __restrict__ alphaS,
        const unsigned* __restrict__ segmax, const float* __restrict__ xp,
        float* __restrict__ aggrN, int N, int E) {
    const int n = blockIdx.x;
    const int t = threadIdx.x;
    const int h = t >> 6, lane = t & 63;
    const char* __restrict__ ea_b = (const char*)ea;
    const char* __restrict__ xp_b = (const char*)xp;
    v2f wcol2[16];
    #pragma unroll
    for (int k2 = 0; k2 < 16; ++k2) {
        wcol2[k2].x = We[(2 * k2)     * HCdim + h * CC + lane];
        wcol2[k2].y = We[(2 * k2 + 1) * HCdim + h * CC + lane];
    }
    const float m = funkey(segmax[n * 3 + h]);
    const float* __restrict__ alphaH = alphaS + (size_t)h * E;
    const int xoff = h * CC * 4 + lane * 4;  // byte offset within an xp row
    const int start = off[n], end = off[n + 1];
    float s = 0.f, acc = 0.f;
    int pos = start;
    for (; pos + 2 <= end; pos += 2) {
        const int2 pe0 = perm[pos];
        const int2 pe1 = perm[pos + 1];
        const int so0 = __builtin_amdgcn_readfirstlane(pe0.x);
        const int eo0 = __builtin_amdgcn_readfirstlane(pe0.y);
        const int so1 = __builtin_amdgcn_readfirstlane(pe1.x);
        const int eo1 = __builtin_amdgcn_readfirstlane(pe1.y);
        const float a0 = alphaH[pos], a1 = alphaH[pos + 1];
        const float4* q0 = (const float4*)(ea_b + eo0);
        const float4* q1 = (const float4*)(ea_b + eo1);
        const float xj0 = *(const float*)(xp_b + so0 + xoff);
        const float xj1 = *(const float*)(xp_b + so1 + xoff);
        v2f d0 = {0.f, 0.f}, d1 = {0.f, 0.f};
        #pragma unroll
        for (int q = 0; q < 8; ++q) {
            const float4 v0 = q0[q];
            const float4 v1 = q1[q];
            v2f lo0 = {v0.x, v0.y}, hi0 = {v0.z, v0.w};
            v2f lo1 = {v1.x, v1.y}, hi1 = {v1.z, v1.w};
            d0 = lo0 * wcol2[2 * q]     + d0;
            d0 = hi0 * wcol2[2 * q + 1] + d0;
            d1 = lo1 * wcol2[2 * q]     + d1;
            d1 = hi1 * wcol2[2 * q + 1] + d1;
        }
        const float p0 = __expf(a0 - m);
        const float p1 = __expf(a1 - m);
        s += p0 + p1;
        acc = fmaf(p0 * (d0.x + d0.y), xj0, acc);
        acc = fmaf(p1 * (d1.x + d1.y), xj1, acc);
    }
    if (pos < end) {
        const int2 pe = perm[pos];
        const int so = __builtin_amdgcn_readfirstlane(pe.x);
        const int eo = __builtin_amdgcn_readfirstlane(pe.y);
        const float a = alphaH[pos];
        const float4* q4 = (const float4*)(ea_b + eo);
        const float xj = *(const float*)(xp_b + so + xoff);
        v2f d = {0.f, 0.f};
        #pragma unroll
        for (int q = 0; q < 8; ++q) {
            const float4 v = q4[q];
            v2f lo = {v.x, v.y}, hi = {v.z, v.w};
            d = lo * wcol2[2 * q]     + d;
            d = hi * wcol2[2 * q + 1] + d;
        }
        const float p = __expf(a - m);
        s += p;
        acc = fmaf(p * (d.x + d.y), xj, acc);
    }
    aggrN[(size_t)n * HCdim + h * CC + lane] = acc / (s + 1e-16f);
}

// K5: out[n,:] = aggrN[n,:] @ Ws + bias   (aggrN already normalized)
__global__ __launch_bounds__(256) void tm_k5(const float* __restrict__ aggrN,
        const float* __restrict__ Ws, const float* __restrict__ bias,
        float* __restrict__ out, int N) {
    __shared__ float wsl[HCdim * CC];   // 48 KiB
    __shared__ float al[4][HCdim];
    const int t = threadIdx.x;
    const int wv = t >> 6, lane = t & 63;
    for (int i = t; i < HCdim * CC; i += 256) wsl[i] = Ws[i];
    const float b = bias[lane];
    for (int base = blockIdx.x * 4; base < N; base += gridDim.x * 4) {
        const int n = base + wv;
        __syncthreads();
        if (n < N) {
            for (int i = lane; i < HCdim; i += 64)
                al[wv][i] = aggrN[(size_t)n * HCdim + i];
        }
        __syncthreads();
        if (n < N) {
            float acc = b;
            #pragma unroll
            for (int k = 0; k < HCdim; ++k)
                acc = fmaf(al[wv][k], wsl[k * CC + lane], acc);
            out[(size_t)n * CC + lane] = acc;
        }
    }
}

extern "C" void kernel_launch(void* const* d_in, const int* in_sizes, int n_in,
                              void* d_out, int out_size, void* d_ws, size_t ws_size,
                              hipStream_t stream) {
    const float* x    = (const float*)d_in[0];
    const int*   ei   = (const int*)d_in[1];
    const float* ea   = (const float*)d_in[2];
    const float* Wn   = (const float*)d_in[3];
    const float* We   = (const float*)d_in[4];
    const float* wt   = (const float*)d_in[5];
    const float* Ws   = (const float*)d_in[6];
    const float* bias = (const float*)d_in[7];
    float* out = (float*)d_out;
    const int N = in_sizes[0] / CC;
    const int E = in_sizes[1] / 2;
    const int nb = (N + 255) / 256;          // scan blocks (<= 256)

    // workspace layout (floats; 16B alignment kept for float4/int2 buffers)
    float* ws = (float*)d_ws;
    size_t o = 0;
    float* xp = ws + o;                  o += (size_t)N * HCdim;   // 38.4 MB
    float* sA = ws + o;                  o += (size_t)N * 8;       // 1.6 MB
    float* u  = ws + o;                  o += 128;
    float* alphaS = ws + o;              o += (size_t)E * HH;      // 9.6 MB
    o += (4 - (o & 3)) & 3;              // 16B align
    int2*  perm = (int2*)(ws + o);       o += (size_t)E * 2;       // 6.4 MB
    int* deg    = (int*)(ws + o);        o += N;
    unsigned* segmax = (unsigned*)(ws + o); o += (size_t)N * HH;
    int* off    = (int*)(ws + o);        o += N + 1;
    int* cursor = (int*)(ws + o);        o += N;
    int* bsum   = (int*)(ws + o);        o += 256;
    int* boff   = (int*)(ws + o);        o += 256;
    o += (4 - (o & 3)) & 3;              // realign
    float* aggrN = ws + o;               o += (size_t)N * HCdim;   // 38.4 MB
    (void)ws_size; (void)n_in; (void)out_size;

    // zero deg + segmax (adjacent)
    (void)hipMemsetAsync(deg, 0, (size_t)N * (1 + HH) * sizeof(int), stream);

    tm_k0<<<1, 96, 0, stream>>>(We, wt, u);
    tm_k1<<<(N + K1_ROWS - 1) / K1_ROWS, 192, 0, stream>>>(x, Wn, wt, xp, sA, N);
    tm_deg<<<(E + 255) / 256, 256, 0, stream>>>(ei, deg, E);
    tm_scanA<<<nb, 256, 0, stream>>>(deg, bsum, N);
    tm_scanB<<<1, 256, 0, stream>>>(bsum, boff, nb);
    tm_scanC<<<nb, 256, 0, stream>>>(deg, boff, off, cursor, N);
    tm_scatter2<<<(E + 255) / 256, 256, 0, stream>>>(ei, ea, u, sA, cursor,
                                                     perm, alphaS, segmax, E);
    tm_agg<<<N, 192, 0, stream>>>(perm, off, ea, We, alphaS, segmax, xp,
                                  aggrN, N, E);
    tm_k5<<<2048, 256, 0, stream>>>(aggrN, Ws, bias, out, N);
}